// Round 1
// baseline (963.015 us; speedup 1.0000x reference)
//
#include <hip/hip_runtime.h>
#include <math.h>

#define NN 50000
#define NE 800000
#define DD 128
#define KIN 256

__device__ __forceinline__ float gelu_exact(float v) {
    return 0.5f * v * (1.0f + erff(v * 0.7071067811865476f));
}

// ---------------- Kernel A: x_proj = concat(x,state) @ W_in + b_in ----------------
// Block: 256 threads, 32 rows x 128 cols per block. LDS-staged A tile.
__global__ __launch_bounds__(256) void proj_kernel(
    const float* __restrict__ x, const float* __restrict__ st,
    const float* __restrict__ W, const float* __restrict__ b,
    float* __restrict__ xp)
{
    __shared__ float a_lds[32][260];   // pad 260: rows 4 apart land 16 banks apart
    const int t = threadIdx.x;
    const int row0 = blockIdx.x * 32;

    // Load 32 rows x 256 k; iteration i loads row i, thread t -> k=t (coalesced).
    #pragma unroll 8
    for (int i = 0; i < 32; ++i) {
        int row = row0 + i;
        float v = 0.f;
        if (row < NN) v = (t < 128) ? x[(size_t)row * 128 + t]
                                    : st[(size_t)row * 128 + (t - 128)];
        a_lds[i][t] = v;
    }
    __syncthreads();

    const int col0 = (t & 31) * 4;   // 32 col-groups x 4 cols
    const int r0   = (t >> 5) * 4;   // 8 row-groups x 4 rows

    float acc[4][4];
    #pragma unroll
    for (int r = 0; r < 4; ++r)
        #pragma unroll
        for (int c = 0; c < 4; ++c)
            acc[r][c] = b[col0 + c];

    #pragma unroll 4
    for (int k0 = 0; k0 < KIN; k0 += 4) {
        float4 av[4];
        #pragma unroll
        for (int r = 0; r < 4; ++r)
            av[r] = *(const float4*)&a_lds[r0 + r][k0];
        #pragma unroll
        for (int kk = 0; kk < 4; ++kk) {
            float4 wv = *(const float4*)&W[(size_t)(k0 + kk) * 128 + col0];
            #pragma unroll
            for (int r = 0; r < 4; ++r) {
                float a = ((const float*)&av[r])[kk];
                acc[r][0] = fmaf(a, wv.x, acc[r][0]);
                acc[r][1] = fmaf(a, wv.y, acc[r][1]);
                acc[r][2] = fmaf(a, wv.z, acc[r][2]);
                acc[r][3] = fmaf(a, wv.w, acc[r][3]);
            }
        }
    }

    #pragma unroll
    for (int r = 0; r < 4; ++r) {
        int row = row0 + r0 + r;
        if (row < NN) {
            float4 o = make_float4(acc[r][0], acc[r][1], acc[r][2], acc[r][3]);
            *(float4*)&xp[(size_t)row * 128 + col0] = o;
        }
    }
}

// ---------------- Kernel B: per-node gate f[n] = softplus(4*(sigmoid(MLP)-0.5)) ----
// One wave per node; lane l holds features 2l, 2l+1.
__global__ __launch_bounds__(256) void gate_kernel(
    const float* __restrict__ xp, const float* __restrict__ W1,
    const float* __restrict__ b1, const float* __restrict__ W2,
    const float* __restrict__ b2, float* __restrict__ f)
{
    __shared__ float w1t[16 * 128];   // transposed: w1t[j*128 + k] = W1[k*16 + j]
    const int t = threadIdx.x;
    for (int i = t; i < 2048; i += 256) {
        int j = i >> 7, k = i & 127;
        w1t[i] = W1[k * 16 + j];
    }
    __syncthreads();

    const int wid = t >> 6, lane = t & 63;
    const int n = blockIdx.x * 4 + wid;
    if (n >= NN) return;

    float2 xv = *(const float2*)&xp[(size_t)n * 128 + lane * 2];
    float p[16];
    #pragma unroll
    for (int j = 0; j < 16; ++j) {
        float2 wv = *(const float2*)&w1t[j * 128 + lane * 2];
        p[j] = fmaf(xv.x, wv.x, xv.y * wv.y);
    }
    #pragma unroll
    for (int off = 32; off >= 1; off >>= 1) {
        #pragma unroll
        for (int j = 0; j < 16; ++j)
            p[j] += __shfl_xor(p[j], off);
    }
    float z = b2[0];
    #pragma unroll
    for (int j = 0; j < 16; ++j) {
        float h = p[j] + b1[j];
        h = (h > 0.f) ? h : 0.1f * h;
        z = fmaf(h, W2[j], z);
    }
    float wd  = 1.f / (1.f + expf(-z));
    float arg = 4.f * (wd - 0.5f);
    float fp  = log1pf(expf(arg));     // softplus, arg in (-2,2): safe
    if (lane == 0) f[n] = fp;
}

// ---------------- Kernel C: edge scatter. One wave per edge. ----------------
__global__ __launch_bounds__(256) void edge_kernel(
    const int* __restrict__ ei, const float* __restrict__ ew,
    const float* __restrict__ xp, const float* __restrict__ f,
    float* __restrict__ acc, float* __restrict__ deg)
{
    const int lane = threadIdx.x & 63;
    const int e = (int)((blockIdx.x * 256u + threadIdx.x) >> 6);
    if (e >= NE) return;
    const int src = ei[e];
    const int dst = ei[NE + e];
    const float w = fminf(ew[e] * f[src], 5.0f);   // w >= 0 always; |w| == w

    float2 m = *(const float2*)&xp[(size_t)src * 128 + lane * 2];
    float* po = &acc[(size_t)dst * 128 + lane * 2];
    unsafeAtomicAdd(po,     m.x * w);
    unsafeAtomicAdd(po + 1, m.y * w);
    if (lane == 0) unsafeAtomicAdd(&deg[dst], w);
}

// ---------------- Kernel D: out = gelu(acc/(deg+eps) + x_proj) ----------------
__global__ __launch_bounds__(256) void final_kernel(
    const float* __restrict__ xp, const float* __restrict__ deg,
    float* __restrict__ out)
{
    int idx = blockIdx.x * 256 + threadIdx.x;
    if (idx >= NN * DD) return;
    int n = idx >> 7;
    float v = out[idx] / (deg[n] + 1e-6f) + xp[idx];
    out[idx] = gelu_exact(v);
}

extern "C" void kernel_launch(void* const* d_in, const int* in_sizes, int n_in,
                              void* d_out, int out_size, void* d_ws, size_t ws_size,
                              hipStream_t stream)
{
    const float* x    = (const float*)d_in[0];
    const float* st   = (const float*)d_in[1];
    const int*   ei   = (const int*)d_in[2];
    const float* ew   = (const float*)d_in[3];
    const float* W_in = (const float*)d_in[4];
    const float* b_in = (const float*)d_in[5];
    const float* W1   = (const float*)d_in[6];
    const float* b1   = (const float*)d_in[7];
    const float* W2   = (const float*)d_in[8];
    const float* b2   = (const float*)d_in[9];
    float* out = (float*)d_out;

    float* xp  = (float*)d_ws;                  // NN*128 floats
    float* f   = xp + (size_t)NN * 128;         // NN floats
    float* deg = f + NN;                        // NN floats

    hipMemsetAsync(d_out, 0, (size_t)NN * DD * sizeof(float), stream);
    hipMemsetAsync(deg, 0, NN * sizeof(float), stream);

    hipLaunchKernelGGL(proj_kernel, dim3((NN + 31) / 32), dim3(256), 0, stream,
                       x, st, W_in, b_in, xp);
    hipLaunchKernelGGL(gate_kernel, dim3((NN + 3) / 4), dim3(256), 0, stream,
                       xp, W1, b1, W2, b2, f);
    hipLaunchKernelGGL(edge_kernel, dim3(NE / 4), dim3(256), 0, stream,
                       ei, ew, xp, f, out, deg);
    hipLaunchKernelGGL(final_kernel, dim3((NN * DD) / 256), dim3(256), 0, stream,
                       xp, deg, out);
}

// Round 2
// 428.673 us; speedup vs baseline: 2.2465x; 2.2465x over previous
//
#include <hip/hip_runtime.h>
#include <math.h>

#define NN 50000
#define NE 800000
#define DD 128
#define KIN 256
#define SCAN_BLOCKS ((NN + 255) / 256)   // 196

__device__ __forceinline__ float gelu_exact(float v) {
    return 0.5f * v * (1.0f + erff(v * 0.7071067811865476f));
}

// ---------------- Kernel A: x_proj = concat(x,state) @ W_in + b_in ----------------
__global__ __launch_bounds__(256) void proj_kernel(
    const float* __restrict__ x, const float* __restrict__ st,
    const float* __restrict__ W, const float* __restrict__ b,
    float* __restrict__ xp)
{
    __shared__ float a_lds[32][260];
    const int t = threadIdx.x;
    const int row0 = blockIdx.x * 32;

    #pragma unroll 8
    for (int i = 0; i < 32; ++i) {
        int row = row0 + i;
        float v = 0.f;
        if (row < NN) v = (t < 128) ? x[(size_t)row * 128 + t]
                                    : st[(size_t)row * 128 + (t - 128)];
        a_lds[i][t] = v;
    }
    __syncthreads();

    const int col0 = (t & 31) * 4;
    const int r0   = (t >> 5) * 4;

    float acc[4][4];
    #pragma unroll
    for (int r = 0; r < 4; ++r)
        #pragma unroll
        for (int c = 0; c < 4; ++c)
            acc[r][c] = b[col0 + c];

    #pragma unroll 4
    for (int k0 = 0; k0 < KIN; k0 += 4) {
        float4 av[4];
        #pragma unroll
        for (int r = 0; r < 4; ++r)
            av[r] = *(const float4*)&a_lds[r0 + r][k0];
        #pragma unroll
        for (int kk = 0; kk < 4; ++kk) {
            float4 wv = *(const float4*)&W[(size_t)(k0 + kk) * 128 + col0];
            #pragma unroll
            for (int r = 0; r < 4; ++r) {
                float a = ((const float*)&av[r])[kk];
                acc[r][0] = fmaf(a, wv.x, acc[r][0]);
                acc[r][1] = fmaf(a, wv.y, acc[r][1]);
                acc[r][2] = fmaf(a, wv.z, acc[r][2]);
                acc[r][3] = fmaf(a, wv.w, acc[r][3]);
            }
        }
    }

    #pragma unroll
    for (int r = 0; r < 4; ++r) {
        int row = row0 + r0 + r;
        if (row < NN) {
            float4 o = make_float4(acc[r][0], acc[r][1], acc[r][2], acc[r][3]);
            *(float4*)&xp[(size_t)row * 128 + col0] = o;
        }
    }
}

// ---------------- Kernel B: per-node gate f[n] = softplus(4*(sigmoid(MLP(xp[n]))-0.5))
__global__ __launch_bounds__(256) void gate_kernel(
    const float* __restrict__ xp, const float* __restrict__ W1,
    const float* __restrict__ b1, const float* __restrict__ W2,
    const float* __restrict__ b2, float* __restrict__ f)
{
    __shared__ float w1t[16 * 128];
    const int t = threadIdx.x;
    for (int i = t; i < 2048; i += 256) {
        int j = i >> 7, k = i & 127;
        w1t[i] = W1[k * 16 + j];
    }
    __syncthreads();

    const int wid = t >> 6, lane = t & 63;
    const int n = blockIdx.x * 4 + wid;
    if (n >= NN) return;

    float2 xv = *(const float2*)&xp[(size_t)n * 128 + lane * 2];
    float p[16];
    #pragma unroll
    for (int j = 0; j < 16; ++j) {
        float2 wv = *(const float2*)&w1t[j * 128 + lane * 2];
        p[j] = fmaf(xv.x, wv.x, xv.y * wv.y);
    }
    #pragma unroll
    for (int off = 32; off >= 1; off >>= 1) {
        #pragma unroll
        for (int j = 0; j < 16; ++j)
            p[j] += __shfl_xor(p[j], off);
    }
    float z = b2[0];
    #pragma unroll
    for (int j = 0; j < 16; ++j) {
        float h = p[j] + b1[j];
        h = (h > 0.f) ? h : 0.1f * h;
        z = fmaf(h, W2[j], z);
    }
    float wd  = 1.f / (1.f + expf(-z));
    float arg = 4.f * (wd - 0.5f);
    float fp  = log1pf(expf(arg));
    if (lane == 0) f[n] = fp;
}

// ---------------- CSR build ----------------
__global__ __launch_bounds__(256) void hist_kernel(
    const int* __restrict__ ei, int* __restrict__ cnt)
{
    int e = blockIdx.x * 256 + threadIdx.x;
    if (e < NE) atomicAdd(&cnt[ei[NE + e]], 1);
}

// per-block exclusive scan; block totals to bsum
__global__ __launch_bounds__(256) void scan1_kernel(
    const int* __restrict__ cnt, int* __restrict__ row_start, int* __restrict__ bsum)
{
    __shared__ int lds[256];
    int i = blockIdx.x * 256 + threadIdx.x;
    int v = (i < NN) ? cnt[i] : 0;
    lds[threadIdx.x] = v;
    __syncthreads();
    #pragma unroll
    for (int off = 1; off < 256; off <<= 1) {
        int t = (threadIdx.x >= off) ? lds[threadIdx.x - off] : 0;
        __syncthreads();
        lds[threadIdx.x] += t;
        __syncthreads();
    }
    if (i < NN) row_start[i] = lds[threadIdx.x] - v;   // exclusive
    if (threadIdx.x == 255) bsum[blockIdx.x] = lds[255];
}

__global__ void scan2_kernel(int* __restrict__ bsum)
{
    if (threadIdx.x == 0 && blockIdx.x == 0) {
        int s = 0;
        for (int i = 0; i < SCAN_BLOCKS; ++i) { int v = bsum[i]; bsum[i] = s; s += v; }
    }
}

// add block offsets; init cursor = row_start (cursor aliases cnt)
__global__ __launch_bounds__(256) void scan3_kernel(
    int* __restrict__ row_start, const int* __restrict__ bsum, int* __restrict__ cursor)
{
    int i = blockIdx.x * 256 + threadIdx.x;
    if (i < NN) {
        int v = row_start[i] + bsum[blockIdx.x];
        row_start[i] = v;
        cursor[i] = v;
    }
}

// scatter edges into CSR order; compute per-edge weight w = min(ew*f[src], 5)
__global__ __launch_bounds__(256) void scatter_kernel(
    const int* __restrict__ ei, const float* __restrict__ ew,
    const float* __restrict__ f, int* __restrict__ cursor,
    int* __restrict__ src_s, float* __restrict__ w_s)
{
    int e = blockIdx.x * 256 + threadIdx.x;
    if (e >= NE) return;
    int src = ei[e];
    int dst = ei[NE + e];
    float w = fminf(ew[e] * f[src], 5.0f);     // w >= 0 always; |w| == w
    int pos = atomicAdd(&cursor[dst], 1);
    src_s[pos] = src;
    w_s[pos]  = w;
}

// ---------------- aggregation + degree-norm + residual + GELU (fused) ----------
// one wave per node; lane l owns features 2l, 2l+1. After scatter, cursor[n] = row end.
__global__ __launch_bounds__(256) void aggregate_kernel(
    const int* __restrict__ row_start, const int* __restrict__ row_end,
    const int* __restrict__ src_s, const float* __restrict__ w_s,
    const float* __restrict__ xp, float* __restrict__ out)
{
    const int wid = threadIdx.x >> 6, lane = threadIdx.x & 63;
    const int n = blockIdx.x * 4 + wid;
    if (n >= NN) return;
    const int beg = row_start[n], end = row_end[n];
    float acc0 = 0.f, acc1 = 0.f, deg = 0.f;
    for (int i = beg; i < end; ++i) {
        int s = src_s[i];
        float w = w_s[i];
        float2 m = *(const float2*)&xp[(size_t)s * 128 + lane * 2];
        acc0 = fmaf(m.x, w, acc0);
        acc1 = fmaf(m.y, w, acc1);
        deg += w;
    }
    float inv = 1.f / (deg + 1e-6f);
    float2 xv = *(const float2*)&xp[(size_t)n * 128 + lane * 2];
    float2 o;
    o.x = gelu_exact(fmaf(acc0, inv, xv.x));
    o.y = gelu_exact(fmaf(acc1, inv, xv.y));
    *(float2*)&out[(size_t)n * 128 + lane * 2] = o;
}

extern "C" void kernel_launch(void* const* d_in, const int* in_sizes, int n_in,
                              void* d_out, int out_size, void* d_ws, size_t ws_size,
                              hipStream_t stream)
{
    const float* x    = (const float*)d_in[0];
    const float* st   = (const float*)d_in[1];
    const int*   ei   = (const int*)d_in[2];
    const float* ew   = (const float*)d_in[3];
    const float* W_in = (const float*)d_in[4];
    const float* b_in = (const float*)d_in[5];
    const float* W1   = (const float*)d_in[6];
    const float* b1   = (const float*)d_in[7];
    const float* W2   = (const float*)d_in[8];
    const float* b2   = (const float*)d_in[9];
    float* out = (float*)d_out;

    // workspace layout (all 4-byte elems): ~32.6 MB
    float* xp        = (float*)d_ws;                    // NN*128
    float* f         = xp + (size_t)NN * 128;           // NN
    int*   cnt_cur   = (int*)(f + NN);                  // NN   (histogram, then cursor)
    int*   row_start = cnt_cur + NN;                    // NN
    int*   bsum      = row_start + NN;                  // 256
    int*   src_s     = bsum + 256;                      // NE
    float* w_s       = (float*)(src_s + NE);            // NE

    hipMemsetAsync(cnt_cur, 0, NN * sizeof(int), stream);

    hipLaunchKernelGGL(proj_kernel, dim3((NN + 31) / 32), dim3(256), 0, stream,
                       x, st, W_in, b_in, xp);
    hipLaunchKernelGGL(gate_kernel, dim3((NN + 3) / 4), dim3(256), 0, stream,
                       xp, W1, b1, W2, b2, f);
    hipLaunchKernelGGL(hist_kernel, dim3((NE + 255) / 256), dim3(256), 0, stream,
                       ei, cnt_cur);
    hipLaunchKernelGGL(scan1_kernel, dim3(SCAN_BLOCKS), dim3(256), 0, stream,
                       cnt_cur, row_start, bsum);
    hipLaunchKernelGGL(scan2_kernel, dim3(1), dim3(64), 0, stream, bsum);
    hipLaunchKernelGGL(scan3_kernel, dim3(SCAN_BLOCKS), dim3(256), 0, stream,
                       row_start, bsum, cnt_cur);
    hipLaunchKernelGGL(scatter_kernel, dim3((NE + 255) / 256), dim3(256), 0, stream,
                       ei, ew, f, cnt_cur, src_s, w_s);
    hipLaunchKernelGGL(aggregate_kernel, dim3((NN + 3) / 4), dim3(256), 0, stream,
                       row_start, cnt_cur, src_s, w_s, xp, out);
}

// Round 3
// 344.593 us; speedup vs baseline: 2.7946x; 1.2440x over previous
//
#include <hip/hip_runtime.h>
#include <math.h>

#define NN 50000
#define NE 800000
#define DD 128
#define KIN 256
#define SCAN_BLOCKS ((NN + 255) / 256)   // 196

typedef __attribute__((ext_vector_type(8))) short short8;
typedef __attribute__((ext_vector_type(4))) float f32x4;

__device__ __forceinline__ float gelu_exact(float v) {
    return 0.5f * v * (1.0f + erff(v * 0.7071067811865476f));
}
__device__ __forceinline__ unsigned short f2bf(float f) {   // RNE bf16
    unsigned int u = __float_as_uint(f);
    unsigned int r = (u + 0x7fffu + ((u >> 16) & 1u)) >> 16;
    return (unsigned short)r;
}
__device__ __forceinline__ float bfhi(unsigned int v) { return __uint_as_float(v & 0xffff0000u); }
__device__ __forceinline__ float bflo(unsigned int v) { return __uint_as_float(v << 16); }

// ---------------- W convert+transpose: Wt[c][k] = bf16(W[k][c]) ----------------
__global__ __launch_bounds__(256) void wconv_kernel(
    const float* __restrict__ W, unsigned short* __restrict__ Wt)
{
    int idx = blockIdx.x * 256 + threadIdx.x;     // 32768 total
    if (idx >= 128 * 256) return;
    int c = idx >> 8, k = idx & 255;
    Wt[idx] = f2bf(W[k * 128 + c]);
}

// ---------------- Kernel A: xpb = bf16(concat(x,state) @ W_in + b_in) via MFMA ----
// 64 rows/block, 4 waves; wave w owns rows w*16..w*16+15, all 128 cols.
// A: [64][256] bf16 LDS (32 KB, XOR-swizzled). B: half-K [128c][128k] bf16 (32 KB).
__global__ __launch_bounds__(256) void proj_mfma_kernel(
    const float* __restrict__ x, const float* __restrict__ st,
    const unsigned short* __restrict__ Wt, const float* __restrict__ b,
    unsigned short* __restrict__ xpb)
{
    __shared__ unsigned short Ald[64 * 256];
    __shared__ unsigned short Bld[128 * 128];
    const int t = threadIdx.x;
    const int lane = t & 63;
    const int w = t >> 6;
    const int row0 = blockIdx.x * 64;

    // stage A (full K): thread t, iter i: local row r=i*8+(t>>5), k=(t&31)*8 (8 f32 -> 8 bf16)
    #pragma unroll
    for (int i = 0; i < 8; ++i) {
        int r = i * 8 + (t >> 5);
        int kf = (t & 31) * 8;
        int grow = row0 + r;
        float v[8];
        if (grow < NN) {
            const float* src = (kf < 128) ? &x[(size_t)grow * 128 + kf]
                                          : &st[(size_t)grow * 128 + (kf - 128)];
            float4 p0 = *(const float4*)src;
            float4 p1 = *(const float4*)(src + 4);
            v[0]=p0.x; v[1]=p0.y; v[2]=p0.z; v[3]=p0.w;
            v[4]=p1.x; v[5]=p1.y; v[6]=p1.z; v[7]=p1.w;
        } else {
            #pragma unroll
            for (int j = 0; j < 8; ++j) v[j] = 0.f;
        }
        short8 h;
        #pragma unroll
        for (int j = 0; j < 8; ++j) h[j] = (short)f2bf(v[j]);
        int byte = (r * 512 + kf * 2) ^ ((r & 7) << 4);
        *(short8*)((char*)Ald + byte) = h;
    }

    // stage B half kh (k rows kh*128..+127): thread t, iter i: c=i*16+(t>>4), k'=(t&15)*8
    auto stageB = [&](int kh) {
        #pragma unroll
        for (int i = 0; i < 8; ++i) {
            int c  = i * 16 + (t >> 4);
            int kq = (t & 15) * 8;
            short8 vv = *(const short8*)&Wt[c * 256 + kh * 128 + kq];
            int byte = (c * 256 + kq * 2) ^ ((c & 7) << 4);
            *(short8*)((char*)Bld + byte) = vv;
        }
    };
    stageB(0);
    __syncthreads();

    f32x4 acc[8];
    #pragma unroll
    for (int ct = 0; ct < 8; ++ct) acc[ct] = (f32x4){0.f, 0.f, 0.f, 0.f};

    const int arow = w * 16 + (lane & 15);     // LDS-local A row
    const int kgrp = (lane >> 4) * 8;          // per-lane k sub-block
    const int cl   = lane & 15;

    #pragma unroll
    for (int kh = 0; kh < 2; ++kh) {
        if (kh == 1) {
            __syncthreads();
            stageB(1);
            __syncthreads();
        }
        #pragma unroll
        for (int k0 = 0; k0 < 128; k0 += 32) {
            int ka = kh * 128 + k0 + kgrp;
            int abyte = (arow * 512 + ka * 2) ^ ((arow & 7) << 4);
            short8 av = *(short8*)((char*)Ald + abyte);
            #pragma unroll
            for (int ct = 0; ct < 8; ++ct) {
                int c = ct * 16 + cl;
                int bbyte = (c * 256 + (k0 + kgrp) * 2) ^ ((c & 7) << 4);
                short8 bv = *(short8*)((char*)Bld + bbyte);
                acc[ct] = __builtin_amdgcn_mfma_f32_16x16x32_bf16(av, bv, acc[ct], 0, 0, 0);
            }
        }
    }

    // epilogue: C/D layout col=lane&15, row=(lane>>4)*4+reg  [m89-verified]
    const int rbase = row0 + w * 16 + ((lane >> 4) << 2);
    #pragma unroll
    for (int ct = 0; ct < 8; ++ct) {
        int col = ct * 16 + cl;
        float bias = b[col];
        #pragma unroll
        for (int r = 0; r < 4; ++r) {
            int row = rbase + r;
            if (row < NN)
                xpb[(size_t)row * 128 + col] = f2bf(acc[ct][r] + bias);
        }
    }
}

// ---------------- Kernel B: per-node gate f[n] = softplus(4*(sigmoid(MLP(xp[n]))-0.5))
__global__ __launch_bounds__(256) void gate_kernel(
    const unsigned short* __restrict__ xpb, const float* __restrict__ W1,
    const float* __restrict__ b1, const float* __restrict__ W2,
    const float* __restrict__ b2, float* __restrict__ f)
{
    __shared__ float w1t[16 * 128];   // w1t[j*128+k] = W1[k*16+j]
    const int t = threadIdx.x;
    for (int i = t; i < 2048; i += 256) {
        int j = i >> 7, k = i & 127;
        w1t[i] = W1[k * 16 + j];
    }
    __syncthreads();

    const int wid = t >> 6, lane = t & 63;
    const int n = blockIdx.x * 4 + wid;
    if (n >= NN) return;

    unsigned int xv = *(const unsigned int*)&xpb[(size_t)n * 128 + lane * 2];
    float x0 = bflo(xv), x1 = bfhi(xv);
    float p[16];
    #pragma unroll
    for (int j = 0; j < 16; ++j) {
        float2 wv = *(const float2*)&w1t[j * 128 + lane * 2];
        p[j] = fmaf(x0, wv.x, x1 * wv.y);
    }
    #pragma unroll
    for (int off = 32; off >= 1; off >>= 1) {
        #pragma unroll
        for (int j = 0; j < 16; ++j)
            p[j] += __shfl_xor(p[j], off);
    }
    float z = b2[0];
    #pragma unroll
    for (int j = 0; j < 16; ++j) {
        float h = p[j] + b1[j];
        h = (h > 0.f) ? h : 0.1f * h;
        z = fmaf(h, W2[j], z);
    }
    float wd  = 1.f / (1.f + expf(-z));
    float arg = 4.f * (wd - 0.5f);
    float fp  = log1pf(expf(arg));
    if (lane == 0) f[n] = fp;
}

// ---------------- CSR build ----------------
__global__ __launch_bounds__(256) void hist_kernel(
    const int* __restrict__ ei, int* __restrict__ cnt)
{
    int e = blockIdx.x * 256 + threadIdx.x;
    if (e < NE) atomicAdd(&cnt[ei[NE + e]], 1);
}

__global__ __launch_bounds__(256) void scan1_kernel(
    const int* __restrict__ cnt, int* __restrict__ row_start, int* __restrict__ bsum)
{
    __shared__ int lds[256];
    int i = blockIdx.x * 256 + threadIdx.x;
    int v = (i < NN) ? cnt[i] : 0;
    lds[threadIdx.x] = v;
    __syncthreads();
    #pragma unroll
    for (int off = 1; off < 256; off <<= 1) {
        int u = (threadIdx.x >= off) ? lds[threadIdx.x - off] : 0;
        __syncthreads();
        lds[threadIdx.x] += u;
        __syncthreads();
    }
    if (i < NN) row_start[i] = lds[threadIdx.x] - v;   // exclusive
    if (threadIdx.x == 255) bsum[blockIdx.x] = lds[255];
}

// block-parallel scan of the 196 block sums (was a 1-thread serial loop)
__global__ __launch_bounds__(256) void scan2_kernel(int* __restrict__ bsum)
{
    __shared__ int lds[256];
    int t = threadIdx.x;
    int v = (t < SCAN_BLOCKS) ? bsum[t] : 0;
    lds[t] = v;
    __syncthreads();
    #pragma unroll
    for (int off = 1; off < 256; off <<= 1) {
        int u = (t >= off) ? lds[t - off] : 0;
        __syncthreads();
        lds[t] += u;
        __syncthreads();
    }
    if (t < SCAN_BLOCKS) bsum[t] = lds[t] - v;         // exclusive
}

__global__ __launch_bounds__(256) void scan3_kernel(
    int* __restrict__ row_start, const int* __restrict__ bsum, int* __restrict__ cursor)
{
    int i = blockIdx.x * 256 + threadIdx.x;
    if (i < NN) {
        int v = row_start[i] + bsum[blockIdx.x];
        row_start[i] = v;
        cursor[i] = v;
    }
}

__global__ __launch_bounds__(256) void scatter_kernel(
    const int* __restrict__ ei, const float* __restrict__ ew,
    const float* __restrict__ f, int* __restrict__ cursor,
    int* __restrict__ src_s, float* __restrict__ w_s)
{
    int e = blockIdx.x * 256 + threadIdx.x;
    if (e >= NE) return;
    int src = ei[e];
    int dst = ei[NE + e];
    float w = fminf(ew[e] * f[src], 5.0f);     // w >= 0 always; |w| == w
    int pos = atomicAdd(&cursor[dst], 1);
    src_s[pos] = src;
    w_s[pos]  = w;
}

// ---------------- aggregation + degree-norm + residual + GELU (fused) ----------
__global__ __launch_bounds__(256) void aggregate_kernel(
    const int* __restrict__ row_start, const int* __restrict__ row_end,
    const int* __restrict__ src_s, const float* __restrict__ w_s,
    const unsigned short* __restrict__ xpb, float* __restrict__ out)
{
    const int wid = threadIdx.x >> 6, lane = threadIdx.x & 63;
    const int n = blockIdx.x * 4 + wid;
    if (n >= NN) return;
    const int beg = row_start[n], end = row_end[n];

    unsigned int rv = *(const unsigned int*)&xpb[(size_t)n * 128 + lane * 2];

    float acc0 = 0.f, acc1 = 0.f, deg = 0.f;
    int i = beg;
    for (; i + 1 < end; i += 2) {
        int   s0 = src_s[i],   s1 = src_s[i + 1];
        float w0 = w_s[i],     w1 = w_s[i + 1];
        unsigned int v0 = *(const unsigned int*)&xpb[(size_t)s0 * 128 + lane * 2];
        unsigned int v1 = *(const unsigned int*)&xpb[(size_t)s1 * 128 + lane * 2];
        acc0 = fmaf(bflo(v0), w0, acc0);
        acc1 = fmaf(bfhi(v0), w0, acc1);
        deg += w0;
        acc0 = fmaf(bflo(v1), w1, acc0);
        acc1 = fmaf(bfhi(v1), w1, acc1);
        deg += w1;
    }
    if (i < end) {
        int s = src_s[i];
        float w = w_s[i];
        unsigned int v = *(const unsigned int*)&xpb[(size_t)s * 128 + lane * 2];
        acc0 = fmaf(bflo(v), w, acc0);
        acc1 = fmaf(bfhi(v), w, acc1);
        deg += w;
    }
    float inv = 1.f / (deg + 1e-6f);
    float2 o;
    o.x = gelu_exact(fmaf(acc0, inv, bflo(rv)));
    o.y = gelu_exact(fmaf(acc1, inv, bfhi(rv)));
    *(float2*)&out[(size_t)n * 128 + lane * 2] = o;
}

extern "C" void kernel_launch(void* const* d_in, const int* in_sizes, int n_in,
                              void* d_out, int out_size, void* d_ws, size_t ws_size,
                              hipStream_t stream)
{
    const float* x    = (const float*)d_in[0];
    const float* st   = (const float*)d_in[1];
    const int*   ei   = (const int*)d_in[2];
    const float* ew   = (const float*)d_in[3];
    const float* W_in = (const float*)d_in[4];
    const float* b_in = (const float*)d_in[5];
    const float* W1   = (const float*)d_in[6];
    const float* b1   = (const float*)d_in[7];
    const float* W2   = (const float*)d_in[8];
    const float* b2   = (const float*)d_in[9];
    float* out = (float*)d_out;

    // workspace layout (~19.9 MB, all offsets 16B-aligned)
    unsigned short* xpb = (unsigned short*)d_ws;            // NN*128 bf16
    float* f         = (float*)(xpb + (size_t)NN * 128);    // NN
    int*   cnt_cur   = (int*)(f + NN);                      // NN (hist -> cursor -> row_end)
    int*   row_start = cnt_cur + NN;                        // NN
    int*   bsum      = row_start + NN;                      // 256
    int*   src_s     = bsum + 256;                          // NE
    float* w_s       = (float*)(src_s + NE);                // NE
    unsigned short* Wt = (unsigned short*)(w_s + NE);       // 128*256 bf16

    hipMemsetAsync(cnt_cur, 0, NN * sizeof(int), stream);

    hipLaunchKernelGGL(wconv_kernel, dim3(128), dim3(256), 0, stream, W_in, Wt);
    hipLaunchKernelGGL(proj_mfma_kernel, dim3((NN + 63) / 64), dim3(256), 0, stream,
                       x, st, Wt, b_in, xpb);
    hipLaunchKernelGGL(gate_kernel, dim3((NN + 3) / 4), dim3(256), 0, stream,
                       xpb, W1, b1, W2, b2, f);
    hipLaunchKernelGGL(hist_kernel, dim3((NE + 255) / 256), dim3(256), 0, stream,
                       ei, cnt_cur);
    hipLaunchKernelGGL(scan1_kernel, dim3(SCAN_BLOCKS), dim3(256), 0, stream,
                       cnt_cur, row_start, bsum);
    hipLaunchKernelGGL(scan2_kernel, dim3(1), dim3(256), 0, stream, bsum);
    hipLaunchKernelGGL(scan3_kernel, dim3(SCAN_BLOCKS), dim3(256), 0, stream,
                       row_start, bsum, cnt_cur);
    hipLaunchKernelGGL(scatter_kernel, dim3((NE + 255) / 256), dim3(256), 0, stream,
                       ei, ew, f, cnt_cur, src_s, w_s);
    hipLaunchKernelGGL(aggregate_kernel, dim3((NN + 3) / 4), dim3(256), 0, stream,
                       row_start, cnt_cur, src_s, w_s, xpb, out);
}

// Round 4
// 278.152 us; speedup vs baseline: 3.4622x; 1.2389x over previous
//
#include <hip/hip_runtime.h>
#include <math.h>

#define NN 50000
#define NE 800000
#define DD 128
#define KIN 256
#define SCAN_BLOCKS ((NN + 255) / 256)   // 196

typedef __attribute__((ext_vector_type(8))) short short8;
typedef __attribute__((ext_vector_type(4))) float f32x4;

__device__ __forceinline__ float gelu_exact(float v) {
    return 0.5f * v * (1.0f + erff(v * 0.7071067811865476f));
}
__device__ __forceinline__ unsigned short f2bf(float f) {   // RNE bf16
    unsigned int u = __float_as_uint(f);
    unsigned int r = (u + 0x7fffu + ((u >> 16) & 1u)) >> 16;
    return (unsigned short)r;
}
__device__ __forceinline__ float bfhi(unsigned int v) { return __uint_as_float(v & 0xffff0000u); }
__device__ __forceinline__ float bflo(unsigned int v) { return __uint_as_float(v << 16); }

// ---- weight prep: Wt[c][k]=bf16(W_in[k][c]) (32768), W1t[j][k]=bf16(W1[k][j]) (2048)
__global__ __launch_bounds__(256) void wconv_kernel(
    const float* __restrict__ W, const float* __restrict__ W1,
    unsigned short* __restrict__ Wt, unsigned short* __restrict__ W1t)
{
    int idx = blockIdx.x * 256 + threadIdx.x;
    if (idx < 128 * 256) {
        int c = idx >> 8, k = idx & 255;
        Wt[idx] = f2bf(W[k * 128 + c]);
    } else if (idx < 128 * 256 + 16 * 128) {
        int i = idx - 128 * 256;
        int j = i >> 7, k = i & 127;
        W1t[i] = f2bf(W1[k * 16 + j]);
    }
}

// ---------------- Kernel A: xpb = bf16(concat(x,state) @ W_in + b_in) via MFMA ----
__global__ __launch_bounds__(256) void proj_mfma_kernel(
    const float* __restrict__ x, const float* __restrict__ st,
    const unsigned short* __restrict__ Wt, const float* __restrict__ b,
    unsigned short* __restrict__ xpb)
{
    __shared__ unsigned short Ald[64 * 256];
    __shared__ unsigned short Bld[128 * 128];
    const int t = threadIdx.x;
    const int lane = t & 63;
    const int w = t >> 6;
    const int row0 = blockIdx.x * 64;

    #pragma unroll
    for (int i = 0; i < 8; ++i) {
        int r = i * 8 + (t >> 5);
        int kf = (t & 31) * 8;
        int grow = row0 + r;
        float v[8];
        if (grow < NN) {
            const float* src = (kf < 128) ? &x[(size_t)grow * 128 + kf]
                                          : &st[(size_t)grow * 128 + (kf - 128)];
            float4 p0 = *(const float4*)src;
            float4 p1 = *(const float4*)(src + 4);
            v[0]=p0.x; v[1]=p0.y; v[2]=p0.z; v[3]=p0.w;
            v[4]=p1.x; v[5]=p1.y; v[6]=p1.z; v[7]=p1.w;
        } else {
            #pragma unroll
            for (int j = 0; j < 8; ++j) v[j] = 0.f;
        }
        short8 h;
        #pragma unroll
        for (int j = 0; j < 8; ++j) h[j] = (short)f2bf(v[j]);
        int byte = (r * 512 + kf * 2) ^ ((r & 7) << 4);
        *(short8*)((char*)Ald + byte) = h;
    }

    auto stageB = [&](int kh) {
        #pragma unroll
        for (int i = 0; i < 8; ++i) {
            int c  = i * 16 + (t >> 4);
            int kq = (t & 15) * 8;
            short8 vv = *(const short8*)&Wt[c * 256 + kh * 128 + kq];
            int byte = (c * 256 + kq * 2) ^ ((c & 7) << 4);
            *(short8*)((char*)Bld + byte) = vv;
        }
    };
    stageB(0);
    __syncthreads();

    f32x4 acc[8];
    #pragma unroll
    for (int ct = 0; ct < 8; ++ct) acc[ct] = (f32x4){0.f, 0.f, 0.f, 0.f};

    const int arow = w * 16 + (lane & 15);
    const int kgrp = (lane >> 4) * 8;
    const int cl   = lane & 15;

    #pragma unroll
    for (int kh = 0; kh < 2; ++kh) {
        if (kh == 1) {
            __syncthreads();
            stageB(1);
            __syncthreads();
        }
        #pragma unroll
        for (int k0 = 0; k0 < 128; k0 += 32) {
            int ka = kh * 128 + k0 + kgrp;
            int abyte = (arow * 512 + ka * 2) ^ ((arow & 7) << 4);
            short8 av = *(short8*)((char*)Ald + abyte);
            #pragma unroll
            for (int ct = 0; ct < 8; ++ct) {
                int c = ct * 16 + cl;
                int bbyte = (c * 256 + (k0 + kgrp) * 2) ^ ((c & 7) << 4);
                short8 bv = *(short8*)((char*)Bld + bbyte);
                acc[ct] = __builtin_amdgcn_mfma_f32_16x16x32_bf16(av, bv, acc[ct], 0, 0, 0);
            }
        }
    }

    const int rbase = row0 + w * 16 + ((lane >> 4) << 2);
    #pragma unroll
    for (int ct = 0; ct < 8; ++ct) {
        int col = ct * 16 + cl;
        float bias = b[col];
        #pragma unroll
        for (int r = 0; r < 4; ++r) {
            int row = rbase + r;
            if (row < NN)
                xpb[(size_t)row * 128 + col] = f2bf(acc[ct][r] + bias);
        }
    }
}

// ---------------- Kernel B: gate via MFMA. One wave = 16 nodes. ----------------
// A-frag: lane holds xpb[base+(lane&15)][(lane>>4)*8 + i], 4 K-blocks of 32.
// C/D: col(lane&15)=hidden j, row=(lane>>4)*4+r = node. [m89 layout]
__global__ __launch_bounds__(256) void gate_mfma_kernel(
    const unsigned short* __restrict__ xpb, const unsigned short* __restrict__ W1t,
    const float* __restrict__ b1, const float* __restrict__ W2,
    const float* __restrict__ b2, float* __restrict__ f)
{
    const int t = threadIdx.x, lane = t & 63, w = t >> 6;
    const int base = blockIdx.x * 64 + w * 16;
    if (base >= NN) return;
    const int m  = lane & 15;
    const int kg = (lane >> 4) * 8;

    int arow = base + m;
    if (arow >= NN) arow = NN - 1;            // clamp; fake nodes discarded at write
    const unsigned short* ap = &xpb[(size_t)arow * 128 + kg];
    const unsigned short* bp = &W1t[m * 128 + kg];

    f32x4 acc = (f32x4){0.f, 0.f, 0.f, 0.f};
    #pragma unroll
    for (int k0 = 0; k0 < 4; ++k0) {
        short8 av = *(const short8*)(ap + k0 * 32);
        short8 bv = *(const short8*)(bp + k0 * 32);
        acc = __builtin_amdgcn_mfma_f32_16x16x32_bf16(av, bv, acc, 0, 0, 0);
    }

    const float bias = b1[m];
    const float w2   = W2[m];
    float zp[4];
    #pragma unroll
    for (int r = 0; r < 4; ++r) {
        float h = acc[r] + bias;
        h = (h > 0.f) ? h : 0.1f * h;
        zp[r] = h * w2;
    }
    #pragma unroll
    for (int off = 1; off <= 8; off <<= 1) {
        #pragma unroll
        for (int r = 0; r < 4; ++r)
            zp[r] += __shfl_xor(zp[r], off);
    }
    if (m == 0) {
        const float bb2 = b2[0];
        #pragma unroll
        for (int r = 0; r < 4; ++r) {
            int node = base + ((lane >> 4) << 2) + r;
            if (node < NN) {
                float z   = zp[r] + bb2;
                float wd  = 1.f / (1.f + expf(-z));
                float arg = 4.f * (wd - 0.5f);
                f[node] = log1pf(expf(arg));      // softplus, arg in (-2,2)
            }
        }
    }
}

// ---------------- CSR build ----------------
__global__ __launch_bounds__(256) void hist_kernel(
    const int* __restrict__ ei, int* __restrict__ cnt)
{
    int e = blockIdx.x * 256 + threadIdx.x;
    if (e < NE) atomicAdd(&cnt[ei[NE + e]], 1);
}

__global__ __launch_bounds__(256) void scan1_kernel(
    const int* __restrict__ cnt, int* __restrict__ row_start, int* __restrict__ bsum)
{
    __shared__ int lds[256];
    int i = blockIdx.x * 256 + threadIdx.x;
    int v = (i < NN) ? cnt[i] : 0;
    lds[threadIdx.x] = v;
    __syncthreads();
    #pragma unroll
    for (int off = 1; off < 256; off <<= 1) {
        int u = (threadIdx.x >= off) ? lds[threadIdx.x - off] : 0;
        __syncthreads();
        lds[threadIdx.x] += u;
        __syncthreads();
    }
    if (i < NN) row_start[i] = lds[threadIdx.x] - v;
    if (threadIdx.x == 255) bsum[blockIdx.x] = lds[255];
}

__global__ __launch_bounds__(256) void scan2_kernel(int* __restrict__ bsum)
{
    __shared__ int lds[256];
    int t = threadIdx.x;
    int v = (t < SCAN_BLOCKS) ? bsum[t] : 0;
    lds[t] = v;
    __syncthreads();
    #pragma unroll
    for (int off = 1; off < 256; off <<= 1) {
        int u = (t >= off) ? lds[t - off] : 0;
        __syncthreads();
        lds[t] += u;
        __syncthreads();
    }
    if (t < SCAN_BLOCKS) bsum[t] = lds[t] - v;
}

__global__ __launch_bounds__(256) void scan3_kernel(
    int* __restrict__ row_start, const int* __restrict__ bsum, int* __restrict__ cursor)
{
    int i = blockIdx.x * 256 + threadIdx.x;
    if (i < NN) {
        int v = row_start[i] + bsum[blockIdx.x];
        row_start[i] = v;
        cursor[i] = v;
    }
}

// scatter edges into CSR order; payload packed (src, w-bits) in one 8B store
__global__ __launch_bounds__(256) void scatter_kernel(
    const int* __restrict__ ei, const float* __restrict__ ew,
    const float* __restrict__ f, int* __restrict__ cursor,
    uint2* __restrict__ sw_s)
{
    int e = blockIdx.x * 256 + threadIdx.x;
    if (e >= NE) return;
    int src = ei[e];
    int dst = ei[NE + e];
    float w = fminf(ew[e] * f[src], 5.0f);     // w >= 0 always; |w| == w
    int pos = atomicAdd(&cursor[dst], 1);
    sw_s[pos] = make_uint2((unsigned)src, __float_as_uint(w));
}

// ---------------- aggregation + degree-norm + residual + GELU (fused) ----------
__global__ __launch_bounds__(256) void aggregate_kernel(
    const int* __restrict__ row_start, const int* __restrict__ row_end,
    const uint2* __restrict__ sw_s, const unsigned short* __restrict__ xpb,
    float* __restrict__ out)
{
    const int wid = threadIdx.x >> 6, lane = threadIdx.x & 63;
    const int n = blockIdx.x * 4 + wid;
    if (n >= NN) return;
    const int beg = row_start[n], end = row_end[n];

    unsigned int rv = *(const unsigned int*)&xpb[(size_t)n * 128 + lane * 2];

    float acc0 = 0.f, acc1 = 0.f, deg = 0.f;
    int i = beg;
    for (; i + 1 < end; i += 2) {
        uint2 e0 = sw_s[i], e1 = sw_s[i + 1];
        float w0 = __uint_as_float(e0.y), w1 = __uint_as_float(e1.y);
        unsigned int v0 = *(const unsigned int*)&xpb[(size_t)e0.x * 128 + lane * 2];
        unsigned int v1 = *(const unsigned int*)&xpb[(size_t)e1.x * 128 + lane * 2];
        acc0 = fmaf(bflo(v0), w0, acc0);
        acc1 = fmaf(bfhi(v0), w0, acc1);
        deg += w0;
        acc0 = fmaf(bflo(v1), w1, acc0);
        acc1 = fmaf(bfhi(v1), w1, acc1);
        deg += w1;
    }
    if (i < end) {
        uint2 e0 = sw_s[i];
        float w = __uint_as_float(e0.y);
        unsigned int v = *(const unsigned int*)&xpb[(size_t)e0.x * 128 + lane * 2];
        acc0 = fmaf(bflo(v), w, acc0);
        acc1 = fmaf(bfhi(v), w, acc1);
        deg += w;
    }
    float inv = 1.f / (deg + 1e-6f);
    float2 o;
    o.x = gelu_exact(fmaf(acc0, inv, bflo(rv)));
    o.y = gelu_exact(fmaf(acc1, inv, bfhi(rv)));
    *(float2*)&out[(size_t)n * 128 + lane * 2] = o;
}

extern "C" void kernel_launch(void* const* d_in, const int* in_sizes, int n_in,
                              void* d_out, int out_size, void* d_ws, size_t ws_size,
                              hipStream_t stream)
{
    const float* x    = (const float*)d_in[0];
    const float* st   = (const float*)d_in[1];
    const int*   ei   = (const int*)d_in[2];
    const float* ew   = (const float*)d_in[3];
    const float* W_in = (const float*)d_in[4];
    const float* b_in = (const float*)d_in[5];
    const float* W1   = (const float*)d_in[6];
    const float* b1   = (const float*)d_in[7];
    const float* W2   = (const float*)d_in[8];
    const float* b2   = (const float*)d_in[9];
    float* out = (float*)d_out;

    // workspace layout (~19.9 MB)
    unsigned short* xpb = (unsigned short*)d_ws;            // NN*128 bf16
    float* f         = (float*)(xpb + (size_t)NN * 128);    // NN
    int*   cnt_cur   = (int*)(f + NN);                      // NN (hist -> cursor -> row_end)
    int*   row_start = cnt_cur + NN;                        // NN
    int*   bsum      = row_start + NN;                      // 256
    uint2* sw_s      = (uint2*)(bsum + 256);                // NE x 8B
    unsigned short* Wt  = (unsigned short*)(sw_s + NE);     // 128*256 bf16
    unsigned short* W1t = Wt + 128 * 256;                   // 16*128 bf16

    hipMemsetAsync(cnt_cur, 0, NN * sizeof(int), stream);

    hipLaunchKernelGGL(wconv_kernel, dim3(136), dim3(256), 0, stream, W_in, W1, Wt, W1t);
    hipLaunchKernelGGL(proj_mfma_kernel, dim3((NN + 63) / 64), dim3(256), 0, stream,
                       x, st, Wt, b_in, xpb);
    hipLaunchKernelGGL(gate_mfma_kernel, dim3((NN + 63) / 64), dim3(256), 0, stream,
                       xpb, W1t, b1, W2, b2, f);
    hipLaunchKernelGGL(hist_kernel, dim3((NE + 255) / 256), dim3(256), 0, stream,
                       ei, cnt_cur);
    hipLaunchKernelGGL(scan1_kernel, dim3(SCAN_BLOCKS), dim3(256), 0, stream,
                       cnt_cur, row_start, bsum);
    hipLaunchKernelGGL(scan2_kernel, dim3(1), dim3(256), 0, stream, bsum);
    hipLaunchKernelGGL(scan3_kernel, dim3(SCAN_BLOCKS), dim3(256), 0, stream,
                       row_start, bsum, cnt_cur);
    hipLaunchKernelGGL(scatter_kernel, dim3((NE + 255) / 256), dim3(256), 0, stream,
                       ei, ew, f, cnt_cur, sw_s);
    hipLaunchKernelGGL(aggregate_kernel, dim3((NN + 3) / 4), dim3(256), 0, stream,
                       row_start, cnt_cur, sw_s, xpb, out);
}

// Round 5
// 253.404 us; speedup vs baseline: 3.8003x; 1.0977x over previous
//
#include <hip/hip_runtime.h>
#include <math.h>

#define NN 50000
#define NE 800000
#define DD 128
#define KIN 256
#define SCAN_BLOCKS ((NN + 255) / 256)     // 196
#define GATE_BLOCKS ((NN + 63) / 64)       // 782
#define WCONV_BLOCKS 136                   // 128 (Wt) + 8 (W1t)
#define HIST_BLOCKS ((NE + 255) / 256)     // 3125

typedef __attribute__((ext_vector_type(8))) short short8;
typedef __attribute__((ext_vector_type(4))) float f32x4;

__device__ __forceinline__ float gelu_exact(float v) {
    return 0.5f * v * (1.0f + erff(v * 0.7071067811865476f));
}
__device__ __forceinline__ unsigned short f2bf(float f) {   // RNE bf16
    unsigned int u = __float_as_uint(f);
    unsigned int r = (u + 0x7fffu + ((u >> 16) & 1u)) >> 16;
    return (unsigned short)r;
}
__device__ __forceinline__ float bfhi(unsigned int v) { return __uint_as_float(v & 0xffff0000u); }
__device__ __forceinline__ float bflo(unsigned int v) { return __uint_as_float(v << 16); }

// ---- L1 (fused): weight prep (blocks 0..135) + dst histogram (blocks 136..) ----
__global__ __launch_bounds__(256) void prep_kernel(
    const float* __restrict__ W, const float* __restrict__ W1,
    unsigned short* __restrict__ Wt, unsigned short* __restrict__ W1t,
    const int* __restrict__ ei, int* __restrict__ cnt)
{
    const int bid = blockIdx.x, t = threadIdx.x;
    if (bid < WCONV_BLOCKS) {
        int idx = bid * 256 + t;
        if (idx < 128 * 256) {
            int c = idx >> 8, k = idx & 255;
            Wt[idx] = f2bf(W[k * 128 + c]);
        } else if (idx < 128 * 256 + 16 * 128) {
            int i = idx - 128 * 256;
            int j = i >> 7, k = i & 127;
            W1t[i] = f2bf(W1[k * 16 + j]);
        }
    } else {
        int e = (bid - WCONV_BLOCKS) * 256 + t;
        if (e < NE) atomicAdd(&cnt[ei[NE + e]], 1);
    }
}

// ---------------- Kernel A: xpb = bf16(concat(x,state) @ W_in + b_in) via MFMA ----
__global__ __launch_bounds__(256) void proj_mfma_kernel(
    const float* __restrict__ x, const float* __restrict__ st,
    const unsigned short* __restrict__ Wt, const float* __restrict__ b,
    unsigned short* __restrict__ xpb)
{
    __shared__ unsigned short Ald[64 * 256];
    __shared__ unsigned short Bld[128 * 128];
    const int t = threadIdx.x;
    const int lane = t & 63;
    const int w = t >> 6;
    const int row0 = blockIdx.x * 64;

    #pragma unroll
    for (int i = 0; i < 8; ++i) {
        int r = i * 8 + (t >> 5);
        int kf = (t & 31) * 8;
        int grow = row0 + r;
        float v[8];
        if (grow < NN) {
            const float* src = (kf < 128) ? &x[(size_t)grow * 128 + kf]
                                          : &st[(size_t)grow * 128 + (kf - 128)];
            float4 p0 = *(const float4*)src;
            float4 p1 = *(const float4*)(src + 4);
            v[0]=p0.x; v[1]=p0.y; v[2]=p0.z; v[3]=p0.w;
            v[4]=p1.x; v[5]=p1.y; v[6]=p1.z; v[7]=p1.w;
        } else {
            #pragma unroll
            for (int j = 0; j < 8; ++j) v[j] = 0.f;
        }
        short8 h;
        #pragma unroll
        for (int j = 0; j < 8; ++j) h[j] = (short)f2bf(v[j]);
        int byte = (r * 512 + kf * 2) ^ ((r & 7) << 4);
        *(short8*)((char*)Ald + byte) = h;
    }

    auto stageB = [&](int kh) {
        #pragma unroll
        for (int i = 0; i < 8; ++i) {
            int c  = i * 16 + (t >> 4);
            int kq = (t & 15) * 8;
            short8 vv = *(const short8*)&Wt[c * 256 + kh * 128 + kq];
            int byte = (c * 256 + kq * 2) ^ ((c & 7) << 4);
            *(short8*)((char*)Bld + byte) = vv;
        }
    };
    stageB(0);
    __syncthreads();

    f32x4 acc[8];
    #pragma unroll
    for (int ct = 0; ct < 8; ++ct) acc[ct] = (f32x4){0.f, 0.f, 0.f, 0.f};

    const int arow = w * 16 + (lane & 15);
    const int kgrp = (lane >> 4) * 8;
    const int cl   = lane & 15;

    #pragma unroll
    for (int kh = 0; kh < 2; ++kh) {
        if (kh == 1) {
            __syncthreads();
            stageB(1);
            __syncthreads();
        }
        #pragma unroll
        for (int k0 = 0; k0 < 128; k0 += 32) {
            int ka = kh * 128 + k0 + kgrp;
            int abyte = (arow * 512 + ka * 2) ^ ((arow & 7) << 4);
            short8 av = *(short8*)((char*)Ald + abyte);
            #pragma unroll
            for (int ct = 0; ct < 8; ++ct) {
                int c = ct * 16 + cl;
                int bbyte = (c * 256 + (k0 + kgrp) * 2) ^ ((c & 7) << 4);
                short8 bv = *(short8*)((char*)Bld + bbyte);
                acc[ct] = __builtin_amdgcn_mfma_f32_16x16x32_bf16(av, bv, acc[ct], 0, 0, 0);
            }
        }
    }

    const int rbase = row0 + w * 16 + ((lane >> 4) << 2);
    #pragma unroll
    for (int ct = 0; ct < 8; ++ct) {
        int col = ct * 16 + cl;
        float bias = b[col];
        #pragma unroll
        for (int r = 0; r < 4; ++r) {
            int row = rbase + r;
            if (row < NN)
                xpb[(size_t)row * 128 + col] = f2bf(acc[ct][r] + bias);
        }
    }
}

// ---- L3 (fused): gate MFMA (blocks 0..781) + scan1 (blocks 782..977) ----
__global__ __launch_bounds__(256) void gate_scan_kernel(
    const unsigned short* __restrict__ xpb, const unsigned short* __restrict__ W1t,
    const float* __restrict__ b1, const float* __restrict__ W2,
    const float* __restrict__ b2, float* __restrict__ f,
    const int* __restrict__ cnt, int* __restrict__ row_start, int* __restrict__ bsum)
{
    __shared__ int lds[256];
    const int t = threadIdx.x;
    if (blockIdx.x < GATE_BLOCKS) {
        const int lane = t & 63, w = t >> 6;
        const int base = blockIdx.x * 64 + w * 16;
        if (base >= NN) return;
        const int m  = lane & 15;
        const int kg = (lane >> 4) * 8;

        int arow = base + m;
        if (arow >= NN) arow = NN - 1;
        const unsigned short* ap = &xpb[(size_t)arow * 128 + kg];
        const unsigned short* bp = &W1t[m * 128 + kg];

        f32x4 acc = (f32x4){0.f, 0.f, 0.f, 0.f};
        #pragma unroll
        for (int k0 = 0; k0 < 4; ++k0) {
            short8 av = *(const short8*)(ap + k0 * 32);
            short8 bv = *(const short8*)(bp + k0 * 32);
            acc = __builtin_amdgcn_mfma_f32_16x16x32_bf16(av, bv, acc, 0, 0, 0);
        }

        const float bias = b1[m];
        const float w2   = W2[m];
        float zp[4];
        #pragma unroll
        for (int r = 0; r < 4; ++r) {
            float h = acc[r] + bias;
            h = (h > 0.f) ? h : 0.1f * h;
            zp[r] = h * w2;
        }
        #pragma unroll
        for (int off = 1; off <= 8; off <<= 1) {
            #pragma unroll
            for (int r = 0; r < 4; ++r)
                zp[r] += __shfl_xor(zp[r], off);
        }
        if (m == 0) {
            const float bb2 = b2[0];
            #pragma unroll
            for (int r = 0; r < 4; ++r) {
                int node = base + ((lane >> 4) << 2) + r;
                if (node < NN) {
                    float z   = zp[r] + bb2;
                    float wd  = 1.f / (1.f + expf(-z));
                    float arg = 4.f * (wd - 0.5f);
                    f[node] = log1pf(expf(arg));
                }
            }
        }
    } else {
        const int sbid = blockIdx.x - GATE_BLOCKS;
        int i = sbid * 256 + t;
        int v = (i < NN) ? cnt[i] : 0;
        lds[t] = v;
        __syncthreads();
        #pragma unroll
        for (int off = 1; off < 256; off <<= 1) {
            int u = (t >= off) ? lds[t - off] : 0;
            __syncthreads();
            lds[t] += u;
            __syncthreads();
        }
        if (i < NN) row_start[i] = lds[t] - v;
        if (t == 255) bsum[sbid] = lds[255];
    }
}

// ---- scan3: each block self-computes its bsum prefix (scan2 eliminated) ----
__global__ __launch_bounds__(256) void scan3_kernel(
    int* __restrict__ row_start, const int* __restrict__ bsum, int* __restrict__ cursor)
{
    __shared__ int lds[256];
    const int t = threadIdx.x;
    int v = (t < SCAN_BLOCKS) ? bsum[t] : 0;
    lds[t] = v;
    __syncthreads();
    #pragma unroll
    for (int off = 1; off < 256; off <<= 1) {
        int u = (t >= off) ? lds[t - off] : 0;
        __syncthreads();
        lds[t] += u;
        __syncthreads();
    }
    int boff = (blockIdx.x == 0) ? 0 : lds[blockIdx.x - 1];
    int i = blockIdx.x * 256 + t;
    if (i < NN) {
        int r = row_start[i] + boff;
        row_start[i] = r;
        cursor[i] = r;
    }
}

// scatter edges into CSR order; payload packed (src, w-bits) in one 8B store
__global__ __launch_bounds__(256) void scatter_kernel(
    const int* __restrict__ ei, const float* __restrict__ ew,
    const float* __restrict__ f, int* __restrict__ cursor,
    uint2* __restrict__ sw_s)
{
    int e = blockIdx.x * 256 + threadIdx.x;
    if (e >= NE) return;
    int src = ei[e];
    int dst = ei[NE + e];
    float w = fminf(ew[e] * f[src], 5.0f);     // w >= 0 always; |w| == w
    int pos = atomicAdd(&cursor[dst], 1);
    sw_s[pos] = make_uint2((unsigned)src, __float_as_uint(w));
}

// ---------------- aggregation + degree-norm + residual + GELU (fused) ----------
// 1 wave/node; 4 x 16-lane groups each gather a DIFFERENT edge per instruction
// (lane: uint4 = 8 bf16 dims; 16 lanes x 16B = full 256B row). unroll 4 ->
// 16 edges in flight per wave. Branchless tail: clamped index + w=0.
__global__ __launch_bounds__(256) void aggregate_kernel(
    const int* __restrict__ row_start, const int* __restrict__ row_end,
    const uint2* __restrict__ sw_s, const unsigned short* __restrict__ xpb,
    float* __restrict__ out)
{
    const int wid = threadIdx.x >> 6, lane = threadIdx.x & 63;
    const int g = lane >> 4;          // edge-group 0..3
    const int s16 = lane & 15;        // dims s16*8 .. s16*8+7
    const int n = blockIdx.x * 4 + wid;
    if (n >= NN) return;
    const int beg = row_start[n], end = row_end[n];

    float a0=0.f,a1=0.f,a2=0.f,a3=0.f,a4=0.f,a5=0.f,a6=0.f,a7=0.f,deg=0.f;

    #pragma unroll 4
    for (int i = beg; i < end; i += 4) {
        int idx = i + g;
        int idc = (idx < NE) ? idx : (NE - 1);
        uint2 sw = sw_s[idc];
        float w = (idx < end) ? __uint_as_float(sw.y) : 0.f;
        uint4 v = *(const uint4*)&xpb[(size_t)sw.x * 128 + s16 * 8];
        a0 = fmaf(bflo(v.x), w, a0);
        a1 = fmaf(bfhi(v.x), w, a1);
        a2 = fmaf(bflo(v.y), w, a2);
        a3 = fmaf(bfhi(v.y), w, a3);
        a4 = fmaf(bflo(v.z), w, a4);
        a5 = fmaf(bfhi(v.z), w, a5);
        a6 = fmaf(bflo(v.w), w, a6);
        a7 = fmaf(bfhi(v.w), w, a7);
        deg += w;
    }
    // reduce across the 4 groups (lane bits 4,5)
    #pragma unroll
    for (int off = 16; off <= 32; off <<= 1) {
        a0 += __shfl_xor(a0, off); a1 += __shfl_xor(a1, off);
        a2 += __shfl_xor(a2, off); a3 += __shfl_xor(a3, off);
        a4 += __shfl_xor(a4, off); a5 += __shfl_xor(a5, off);
        a6 += __shfl_xor(a6, off); a7 += __shfl_xor(a7, off);
        deg += __shfl_xor(deg, off);
    }

    float inv = 1.f / (deg + 1e-6f);
    // each lane finalizes 2 dims: d = s16*8 + g*2 + {0,1}
    float e0 = (g == 0) ? a0 : (g == 1) ? a2 : (g == 2) ? a4 : a6;
    float e1 = (g == 0) ? a1 : (g == 1) ? a3 : (g == 2) ? a5 : a7;
    unsigned int rv = *(const unsigned int*)&xpb[(size_t)n * 128 + s16 * 8 + g * 2];
    float2 o;
    o.x = gelu_exact(fmaf(e0, inv, bflo(rv)));
    o.y = gelu_exact(fmaf(e1, inv, bfhi(rv)));
    *(float2*)&out[(size_t)n * 128 + s16 * 8 + g * 2] = o;
}

extern "C" void kernel_launch(void* const* d_in, const int* in_sizes, int n_in,
                              void* d_out, int out_size, void* d_ws, size_t ws_size,
                              hipStream_t stream)
{
    const float* x    = (const float*)d_in[0];
    const float* st   = (const float*)d_in[1];
    const int*   ei   = (const int*)d_in[2];
    const float* ew   = (const float*)d_in[3];
    const float* W_in = (const float*)d_in[4];
    const float* b_in = (const float*)d_in[5];
    const float* W1   = (const float*)d_in[6];
    const float* b1   = (const float*)d_in[7];
    const float* W2   = (const float*)d_in[8];
    const float* b2   = (const float*)d_in[9];
    float* out = (float*)d_out;

    // workspace layout (~19.9 MB)
    unsigned short* xpb = (unsigned short*)d_ws;            // NN*128 bf16
    float* f         = (float*)(xpb + (size_t)NN * 128);    // NN
    int*   cnt_cur   = (int*)(f + NN);                      // NN (hist -> cursor -> row_end)
    int*   row_start = cnt_cur + NN;                        // NN
    int*   bsum      = row_start + NN;                      // 256
    uint2* sw_s      = (uint2*)(bsum + 256);                // NE x 8B
    unsigned short* Wt  = (unsigned short*)(sw_s + NE);     // 128*256 bf16
    unsigned short* W1t = Wt + 128 * 256;                   // 16*128 bf16

    hipMemsetAsync(cnt_cur, 0, NN * sizeof(int), stream);

    hipLaunchKernelGGL(prep_kernel, dim3(WCONV_BLOCKS + HIST_BLOCKS), dim3(256), 0, stream,
                       W_in, W1, Wt, W1t, ei, cnt_cur);
    hipLaunchKernelGGL(proj_mfma_kernel, dim3((NN + 63) / 64), dim3(256), 0, stream,
                       x, st, Wt, b_in, xpb);
    hipLaunchKernelGGL(gate_scan_kernel, dim3(GATE_BLOCKS + SCAN_BLOCKS), dim3(256), 0, stream,
                       xpb, W1t, b1, W2, b2, f, cnt_cur, row_start, bsum);
    hipLaunchKernelGGL(scan3_kernel, dim3(SCAN_BLOCKS), dim3(256), 0, stream,
                       row_start, bsum, cnt_cur);
    hipLaunchKernelGGL(scatter_kernel, dim3(HIST_BLOCKS), dim3(256), 0, stream,
                       ei, ew, f, cnt_cur, sw_s);
    hipLaunchKernelGGL(aggregate_kernel, dim3((NN + 3) / 4), dim3(256), 0, stream,
                       row_start, cnt_cur, sw_s, xpb, out);
}